// Round 12
// baseline (296.369 us; speedup 1.0000x reference)
//
#include <hip/hip_runtime.h>
#include <hip/hip_bf16.h>

#define T_TOKENS 65536
#define D_DIM 256
#define H_DIM 1024
#define E_NUM 8
#define MT 256
#define NTILE (T_TOKENS / MT)  // 256 tiles/expert: covers worst-case routing skew
#define HC 32
#define NCHUNK 32              // H_DIM / HC
#define GTB 64                 // gate tokens per block

typedef __attribute__((ext_vector_type(4))) float f32x4;
typedef __attribute__((ext_vector_type(8))) short s16x8;
typedef __attribute__((ext_vector_type(4))) unsigned int u32x4;
typedef __attribute__((ext_vector_type(4))) unsigned short u16x4;
typedef __attribute__((address_space(3))) unsigned int lds_u32;
typedef const __attribute__((address_space(1))) unsigned int glb_u32;

#define MFMA __builtin_amdgcn_mfma_f32_16x16x32_bf16

__device__ __forceinline__ unsigned short f2bf(float f){
  union { float f; unsigned u; } v; v.f = f;
  unsigned r = v.u + 0x7FFFu + ((v.u >> 16) & 1u);
  return (unsigned short)(r >> 16);
}
__device__ __forceinline__ float bf2f(unsigned short h){
  return __uint_as_float((unsigned)h << 16);
}
__device__ __forceinline__ unsigned cvtpk(float lo, float hi){
  unsigned r;
  asm("v_cvt_pk_bf16_f32 %0, %1, %2" : "=v"(r) : "v"(lo), "v"(hi));
  return r;
}
__device__ __forceinline__ unsigned long long pack4(f32x4 v){
  return (unsigned long long)f2bf(v.x)
       | ((unsigned long long)f2bf(v.y) << 16)
       | ((unsigned long long)f2bf(v.z) << 32)
       | ((unsigned long long)f2bf(v.w) << 48);
}

// one 4-float unit of weight conversion into the FRAGMENT-MAJOR chunk image
// (identical to R10's — proven conflict-free).
// chunk(e,c) = 32KB:
//  [W1f: 16 fragments (ks*2+mi) x 1KB; lane=qj*16+mrow holds 16B =
//   W1[h=mi*16+mrow][d=ks*32+qj*8 .. +7]]
//  [W2f at +16384: 16 m-tiles x 1KB; lane=qj*16+(d&15) holds 16B with
//   byte j'*2 = W2[d=m*16+(d&15)][h=mi*16+qj*4+j], j'=mi*4+j]
__device__ __forceinline__ void cvt_unit(int i, const float* __restrict__ W1,
                                         const float* __restrict__ W2,
                                         char* __restrict__ wsw){
  const int N1 = (E_NUM * H_DIM * D_DIM) / 4;      // 524288
  unsigned long long pk;
  size_t off;
  if (i < N1){
    pk = pack4(((const f32x4*)W1)[i]);
    int idx = i << 2;
    int e  = idx >> 18;
    int h  = (idx >> 8) & (H_DIM - 1);
    int d0 = idx & (D_DIM - 1);
    int c = h >> 5, mi = (h >> 4) & 1, mrow = h & 15;
    int ks = d0 >> 5, qj = (d0 >> 3) & 3, e2 = d0 & 7;
    off = ((size_t)(e * NCHUNK + c) << 15)
        + (size_t)(((ks*2 + mi) << 10) + ((qj*16 + mrow) << 4) + (e2 << 1));
  } else {
    pk = pack4(((const f32x4*)W2)[i - N1]);
    int idx = (i - N1) << 2;
    int e   = idx >> 18;
    int d   = (idx >> 10) & (D_DIM - 1);
    int h0  = idx & (H_DIM - 1);
    int c   = h0 >> 5;
    int h32 = h0 & 31;
    int mi = (h32 >> 4) & 1, qj = (h32 >> 2) & 3;
    off = ((size_t)(e * NCHUNK + c) << 15) + 16384
        + (size_t)(((d >> 4) << 10) + ((qj * 16 + (d & 15)) << 4) + (mi << 3));
  }
  *(unsigned long long*)(wsw + off) = pk;
}

// ---- gate (+fused weight conversion): scores, top-2, softmax, routing ----
__global__ __launch_bounds__(256) void gate_kernel(
    const float* __restrict__ x, const float* __restrict__ Wg,
    const float* __restrict__ bg,
    const float* __restrict__ W1, const float* __restrict__ W2,
    char* __restrict__ wsw,
    int* __restrict__ counts, int* __restrict__ tok_ids, float* __restrict__ rrec)
{
  __shared__ int lcnt[E_NUM];
  __shared__ int lbase[E_NUM];
  __shared__ unsigned char aexp[GTB * 2];
  __shared__ short         apos[GTB * 2];

  int tid = threadIdx.x, wave = tid >> 6, lane = tid & 63;

  // fused weight conversion: 4 units per thread
  int gthr = blockIdx.x * 256 + tid;
#pragma unroll
  for (int j = 0; j < 4; ++j)
    cvt_unit(gthr + j * ((T_TOKENS / GTB) * 256), W1, W2, wsw);

  if (tid < E_NUM) lcnt[tid] = 0;
  __syncthreads();

  int t0 = blockIdx.x * GTB;
#pragma unroll 1
  for (int i = 0; i < GTB / 4; ++i){
    int tl = wave * (GTB / 4) + i;
    int t = t0 + tl;
    f32x4 xv = *(const f32x4*)(x + (size_t)t * D_DIM + 4*lane);
    float s[E_NUM];
#pragma unroll
    for (int e = 0; e < E_NUM; ++e){
      f32x4 w = *(const f32x4*)(Wg + e*D_DIM + 4*lane);
      s[e] = xv.x*w.x + xv.y*w.y + xv.z*w.z + xv.w*w.w;
    }
#pragma unroll
    for (int off = 32; off; off >>= 1){
#pragma unroll
      for (int e = 0; e < E_NUM; ++e) s[e] += __shfl_xor(s[e], off);
    }
#pragma unroll
    for (int e = 0; e < E_NUM; ++e) s[e] += bg[e];
    int e0 = 0; float v0 = s[0];
#pragma unroll
    for (int e = 1; e < E_NUM; ++e) if (s[e] > v0){ v0 = s[e]; e0 = e; }
    int e1 = -1; float v1 = -3.4e38f;
#pragma unroll
    for (int e = 0; e < E_NUM; ++e){
      if (e == e0) continue;
      if (s[e] > v1){ v1 = s[e]; e1 = e; }
    }
    float ex = __expf(v1 - v0);
    float inv = 1.f / (1.f + ex);
    float p0 = inv, p1 = ex * inv;
    if (lane == 0){
      int li = tl * 2;
      int pos0 = atomicAdd(&lcnt[e0], 1);
      int pos1 = atomicAdd(&lcnt[e1], 1);
      aexp[li]   = (unsigned char)e0; apos[li]   = (short)pos0;
      aexp[li+1] = (unsigned char)e1; apos[li+1] = (short)pos1;
      f32x4 rr; rr.x = p0; rr.y = p1; rr.z = (float)e0; rr.w = (float)e1;
      *(f32x4*)(rrec + (size_t)t * 4) = rr;
    }
  }
  __syncthreads();
  if (tid < E_NUM) lbase[tid] = atomicAdd(counts + tid*16, lcnt[tid]);
  __syncthreads();
  if (tid < GTB * 2){
    int t = t0 + (tid >> 1);
    int e = aexp[tid];
    int idx = lbase[e] + apos[tid];
    tok_ids[e*T_TOKENS + idx] = t | ((tid & 1) << 16);   // token | which-bit
  }
}

// ---- grouped FFN: ONE 512-thread block per CU slot. 256 tokens/block,
//      8 waves x 32 tokens, h in registers. One shared fragment-major W
//      double-buffer (2 x 32KB) staged once per chunk (vs 2x in R5-R10).
//      One barrier per chunk. launch_bounds(512,2) = 256-reg cap (R5 regime).
__global__ __launch_bounds__(512, 2) void ffn_kernel(
  const float* __restrict__ x, const char* __restrict__ wsw,
  const float* __restrict__ b1,
  const int* __restrict__ counts, const int* __restrict__ tok_ids,
  unsigned short* __restrict__ yslot)
{
  const int e    = blockIdx.x & 7;           // expert -> XCD pinning
  const int tile = blockIdx.x >> 3;
  const int cnt  = counts[e * 16];
  const int base = tile * MT;
  if (base >= cnt) return;                   // empty tile: cheap early exit

  __shared__ __align__(1024) unsigned short Ws[2][16384];   // 2 x 32KB chunk
  __shared__ __align__(16)   float b1s[H_DIM];              // 4KB
  __shared__ int sTok[MT];                                  // 1KB

  const int tid = threadIdx.x, wave = tid >> 6, lane = tid & 63;
  const int mrow = lane & 15, qj = lane >> 4;
  const char* wexp = wsw + ((size_t)(e * NCHUNK) << 15);

  // whole 32KB chunk staged cooperatively by 8 waves: 4 x 1KB per wave
  auto stage = [&](int c, int buf){
    const char* src = wexp + ((size_t)c << 15);
    char* dst = (char*)&Ws[buf][0];
#pragma unroll
    for (int i = 0; i < 4; ++i){
      int ub = i * 8192 + wave * 1024;
      __builtin_amdgcn_global_load_lds(
        (glb_u32*)(src + ub + lane * 16),
        (lds_u32*)(dst + ub), 16, 0, 0);
    }
  };

  if (tid < MT){
    int idx = base + tid;
    sTok[tid] = (idx < cnt) ? tok_ids[e*T_TOKENS + idx] : -1;
  }
  if (tid < 256) *(f32x4*)&b1s[tid * 4] = ((const f32x4*)(b1 + e*H_DIM))[tid];
  __syncthreads();

  // prologue: stage chunk 0
  stage(0, 0);

  // gather x B-fragments into registers (32 tokens/wave, full D)
  s16x8 afr[2][8];
#pragma unroll
  for (int ti = 0; ti < 2; ++ti){
    int ent = sTok[wave*32 + ti*16 + mrow];
    int tk = ent & 0xFFFF;
    const f32x4* src = (const f32x4*)(x + (size_t)(ent < 0 ? 0 : tk) * D_DIM);
#pragma unroll
    for (int k = 0; k < 8; ++k){
      f32x4 a = src[k*8 + qj*2];
      f32x4 b = src[k*8 + qj*2 + 1];
      s16x8 f;
      f[0]=(short)f2bf(a.x); f[1]=(short)f2bf(a.y); f[2]=(short)f2bf(a.z); f[3]=(short)f2bf(a.w);
      f[4]=(short)f2bf(b.x); f[5]=(short)f2bf(b.y); f[6]=(short)f2bf(b.z); f[7]=(short)f2bf(b.w);
      if (ent < 0) f = (s16x8)(short)0;
      afr[ti][k] = f;
    }
  }

  const int lb = lane * 16;   // fragment-major per-lane byte offset

  asm volatile("s_waitcnt vmcnt(0) lgkmcnt(0)" ::: "memory");
  __builtin_amdgcn_s_barrier();

  f32x4 yacc[16][2];
#pragma unroll
  for (int m = 0; m < 16; ++m){
    yacc[m][0] = (f32x4){0.f,0.f,0.f,0.f};
    yacc[m][1] = (f32x4){0.f,0.f,0.f,0.f};
  }

  int buf = 0;
#pragma unroll 1
  for (int c = 0; c < NCHUNK; ++c){
    // issue next chunk's staging first (full chunk of compute cover)
    if (c + 1 < NCHUNK) stage(c + 1, buf ^ 1);

    const char* Wb = (const char*)&Ws[buf][0];

    // ---- phase 1: h = W1(c) x^T  (conflict-free LDS reads, imm offsets) ----
    __builtin_amdgcn_s_setprio(1);
    f32x4 hacc[2][2];
    hacc[0][0] = (f32x4){0.f,0.f,0.f,0.f}; hacc[0][1] = (f32x4){0.f,0.f,0.f,0.f};
    hacc[1][0] = (f32x4){0.f,0.f,0.f,0.f}; hacc[1][1] = (f32x4){0.f,0.f,0.f,0.f};
#pragma unroll
    for (int ks = 0; ks < 8; ++ks){
      s16x8 wa = *(const s16x8*)(Wb + lb + (ks*2    )*1024);
      s16x8 wb = *(const s16x8*)(Wb + lb + (ks*2 + 1)*1024);
      hacc[0][0] = MFMA(wa, afr[0][ks], hacc[0][0], 0, 0, 0);
      hacc[0][1] = MFMA(wa, afr[1][ks], hacc[0][1], 0, 0, 0);
      hacc[1][0] = MFMA(wb, afr[0][ks], hacc[1][0], 0, 0, 0);
      hacc[1][1] = MFMA(wb, afr[1][ks], hacc[1][1], 0, 0, 0);
    }
    __builtin_amdgcn_s_setprio(0);

    // ---- bias + relu + pack to bf16 B-fragments (in registers) ----
    f32x4 bv0 = *(const f32x4*)&b1s[c*32 + qj*4];
    f32x4 bv1 = *(const f32x4*)&b1s[c*32 + 16 + qj*4];
    s16x8 pb0, pb1;
    {
      f32x4 h0 = hacc[0][0], h1 = hacc[1][0];
      h0.x = fmaxf(h0.x + bv0.x, 0.f); h0.y = fmaxf(h0.y + bv0.y, 0.f);
      h0.z = fmaxf(h0.z + bv0.z, 0.f); h0.w = fmaxf(h0.w + bv0.w, 0.f);
      h1.x = fmaxf(h1.x + bv1.x, 0.f); h1.y = fmaxf(h1.y + bv1.y, 0.f);
      h1.z = fmaxf(h1.z + bv1.z, 0.f); h1.w = fmaxf(h1.w + bv1.w, 0.f);
      u32x4 pw;
      pw.x = cvtpk(h0.x, h0.y); pw.y = cvtpk(h0.z, h0.w);
      pw.z = cvtpk(h1.x, h1.y); pw.w = cvtpk(h1.z, h1.w);
      pb0 = __builtin_bit_cast(s16x8, pw);
    }
    {
      f32x4 h0 = hacc[0][1], h1 = hacc[1][1];
      h0.x = fmaxf(h0.x + bv0.x, 0.f); h0.y = fmaxf(h0.y + bv0.y, 0.f);
      h0.z = fmaxf(h0.z + bv0.z, 0.f); h0.w = fmaxf(h0.w + bv0.w, 0.f);
      h1.x = fmaxf(h1.x + bv1.x, 0.f); h1.y = fmaxf(h1.y + bv1.y, 0.f);
      h1.z = fmaxf(h1.z + bv1.z, 0.f); h1.w = fmaxf(h1.w + bv1.w, 0.f);
      u32x4 pw;
      pw.x = cvtpk(h0.x, h0.y); pw.y = cvtpk(h0.z, h0.w);
      pw.z = cvtpk(h1.x, h1.y); pw.w = cvtpk(h1.z, h1.w);
      pb1 = __builtin_bit_cast(s16x8, pw);
    }

    // ---- phase 2: y += W2f(c) h  (conflict-free LDS reads) ----
    __builtin_amdgcn_s_setprio(1);
    const char* Wl = Wb + 16384;
#pragma unroll
    for (int m = 0; m < 16; ++m){
      s16x8 lf = *(const s16x8*)(Wl + lb + m*1024);
      yacc[m][0] = MFMA(lf, pb0, yacc[m][0], 0, 0, 0);
      yacc[m][1] = MFMA(lf, pb1, yacc[m][1], 0, 0, 0);
    }
    __builtin_amdgcn_s_setprio(0);

    // one barrier per chunk; staged loads had a full chunk of cover
    asm volatile("s_waitcnt vmcnt(0) lgkmcnt(0)" ::: "memory");
    __builtin_amdgcn_s_barrier();
    buf ^= 1;
  }

  // ---- store: yslot[2*tok+which][d] = bf16(y), packed b32, no atomics ----
#pragma unroll
  for (int ti = 0; ti < 2; ++ti){
    int ent = sTok[wave*32 + ti*16 + mrow];
    if (ent < 0) continue;
    int slot = ((ent & 0xFFFF) << 1) | ((ent >> 16) & 1);
    unsigned short* dst = yslot + (size_t)slot * 256;
#pragma unroll
    for (int m = 0; m < 16; ++m){
      unsigned lo = cvtpk(yacc[m][ti][0], yacc[m][ti][1]);
      unsigned hi = cvtpk(yacc[m][ti][2], yacc[m][ti][3]);
      *(unsigned*)(dst + m*16 + qj*4)     = lo;   // d = m*16 + qj*4 + {0,1}
      *(unsigned*)(dst + m*16 + qj*4 + 2) = hi;   // d = ... + {2,3}
    }
  }
}

// ---- combine: out[t] = p0*(y0+b2[e0]) + p1*(y1+b2[e1]); in-place over slots ----
__global__ __launch_bounds__(256) void combine_kernel(
    const float* __restrict__ rrec, const float* __restrict__ b2,
    float* __restrict__ out)
{
  int t = blockIdx.x * 4 + (threadIdx.x >> 6);
  int lane = threadIdx.x & 63;
  f32x4 rr = *(const f32x4*)(rrec + (size_t)t * 4);
  float p0 = rr.x, p1 = rr.y;
  int e0 = (int)rr.z, e1 = (int)rr.w;
  const u16x4* s0 = (const u16x4*)((const unsigned short*)out + (size_t)t * 512);
  u16x4 a = s0[lane];        // slot 2t   : cols lane*4..+3
  u16x4 b = s0[64 + lane];   // slot 2t+1
  f32x4 z0 = *(const f32x4*)(b2 + e0*D_DIM + 4*lane);
  f32x4 z1 = *(const f32x4*)(b2 + e1*D_DIM + 4*lane);
  f32x4 o;
  o.x = p0*(bf2f(a.x) + z0.x) + p1*(bf2f(b.x) + z1.x);
  o.y = p0*(bf2f(a.y) + z0.y) + p1*(bf2f(b.y) + z1.y);
  o.z = p0*(bf2f(a.z) + z0.z) + p1*(bf2f(b.z) + z1.z);
  o.w = p0*(bf2f(a.w) + z0.w) + p1*(bf2f(b.w) + z1.w);
  *(f32x4*)(out + (size_t)t * D_DIM + 4*lane) = o;
}

extern "C" void kernel_launch(void* const* d_in, const int* in_sizes, int n_in,
                              void* d_out, int out_size, void* d_ws, size_t ws_size,
                              hipStream_t stream) {
  const float* x  = (const float*)d_in[0];
  const float* Wg = (const float*)d_in[1];
  const float* bg = (const float*)d_in[2];
  const float* W1 = (const float*)d_in[3];
  const float* b1 = (const float*)d_in[4];
  const float* W2 = (const float*)d_in[5];
  const float* b2 = (const float*)d_in[6];
  float* out = (float*)d_out;
  char* ws = (char*)d_ws;

  char*  wsw     = ws;                        // 8,388,608 B fragment-major weights
  int*   counts  = (int*)  (ws + 8388608);    // 512 B (8 x 64B lines)
  int*   tok_ids = (int*)  (ws + 8389632);    // 2,097,152 B
  float* rrec    = (float*)(ws + 10486784);   // 1,048,576 B (f32x4 per token)

  hipMemsetAsync(counts, 0, 512, stream);
  gate_kernel<<<T_TOKENS/GTB, 256, 0, stream>>>(x, Wg, bg, W1, W2, wsw,
                                                counts, tok_ids, rrec);
  ffn_kernel<<<E_NUM * NTILE, 512, 0, stream>>>(x, wsw, b1, counts, tok_ids,
                                                (unsigned short*)d_out);
  combine_kernel<<<T_TOKENS/4, 256, 0, stream>>>(rrec, b2, out);
}

// Round 13
// 264.555 us; speedup vs baseline: 1.1203x; 1.1203x over previous
//
#include <hip/hip_runtime.h>
#include <hip/hip_bf16.h>

#define T_TOKENS 65536
#define D_DIM 256
#define H_DIM 1024
#define E_NUM 8
#define MT 128
#define NTILE (T_TOKENS / MT)  // full worst-case coverage (R11 lesson)
#define HC 32
#define NCHUNK 32              // H_DIM / HC
#define GTB 64                 // gate tokens per block

typedef __attribute__((ext_vector_type(4))) float f32x4;
typedef __attribute__((ext_vector_type(8))) short s16x8;
typedef __attribute__((ext_vector_type(4))) unsigned int u32x4;
typedef __attribute__((ext_vector_type(4))) unsigned short u16x4;
typedef __attribute__((address_space(3))) unsigned int lds_u32;
typedef const __attribute__((address_space(1))) unsigned int glb_u32;

#define MFMA __builtin_amdgcn_mfma_f32_16x16x32_bf16

__device__ __forceinline__ unsigned short f2bf(float f){
  union { float f; unsigned u; } v; v.f = f;
  unsigned r = v.u + 0x7FFFu + ((v.u >> 16) & 1u);
  return (unsigned short)(r >> 16);
}
__device__ __forceinline__ float bf2f(unsigned short h){
  return __uint_as_float((unsigned)h << 16);
}
__device__ __forceinline__ unsigned cvtpk(float lo, float hi){
  unsigned r;
  asm("v_cvt_pk_bf16_f32 %0, %1, %2" : "=v"(r) : "v"(lo), "v"(hi));
  return r;
}
__device__ __forceinline__ unsigned long long pack4(f32x4 v){
  return (unsigned long long)f2bf(v.x)
       | ((unsigned long long)f2bf(v.y) << 16)
       | ((unsigned long long)f2bf(v.z) << 32)
       | ((unsigned long long)f2bf(v.w) << 48);
}

// FRAGMENT-MAJOR chunk image (R10/R12 layout — proven correct, conflict-free).
// chunk(e,c) = 32KB = [W1f 16KB: frag (ks*2+mi) x 1KB, lane 16B]
//                   + [W2f 16KB at +16384: m-tile x 1KB, lane 16B]
__device__ __forceinline__ void cvt_unit(int i, const float* __restrict__ W1,
                                         const float* __restrict__ W2,
                                         char* __restrict__ wsw){
  const int N1 = (E_NUM * H_DIM * D_DIM) / 4;      // 524288
  unsigned long long pk;
  size_t off;
  if (i < N1){
    pk = pack4(((const f32x4*)W1)[i]);
    int idx = i << 2;
    int e  = idx >> 18;
    int h  = (idx >> 8) & (H_DIM - 1);
    int d0 = idx & (D_DIM - 1);
    int c = h >> 5, mi = (h >> 4) & 1, mrow = h & 15;
    int ks = d0 >> 5, qj = (d0 >> 3) & 3, e2 = d0 & 7;
    off = ((size_t)(e * NCHUNK + c) << 15)
        + (size_t)(((ks*2 + mi) << 10) + ((qj*16 + mrow) << 4) + (e2 << 1));
  } else {
    pk = pack4(((const f32x4*)W2)[i - N1]);
    int idx = (i - N1) << 2;
    int e   = idx >> 18;
    int d   = (idx >> 10) & (D_DIM - 1);
    int h0  = idx & (H_DIM - 1);
    int c   = h0 >> 5;
    int h32 = h0 & 31;
    int mi = (h32 >> 4) & 1, qj = (h32 >> 2) & 3;
    off = ((size_t)(e * NCHUNK + c) << 15) + 16384
        + (size_t)(((d >> 4) << 10) + ((qj * 16 + (d & 15)) << 4) + (mi << 3));
  }
  *(unsigned long long*)(wsw + off) = pk;
}

// ---- gate (+fused weight conversion): scores, top-2, softmax, routing ----
__global__ __launch_bounds__(256) void gate_kernel(
    const float* __restrict__ x, const float* __restrict__ Wg,
    const float* __restrict__ bg,
    const float* __restrict__ W1, const float* __restrict__ W2,
    char* __restrict__ wsw,
    int* __restrict__ counts, int* __restrict__ tok_ids, float* __restrict__ rrec)
{
  __shared__ int lcnt[E_NUM];
  __shared__ int lbase[E_NUM];
  __shared__ unsigned char aexp[GTB * 2];
  __shared__ short         apos[GTB * 2];

  int tid = threadIdx.x, wave = tid >> 6, lane = tid & 63;

  int gthr = blockIdx.x * 256 + tid;
#pragma unroll
  for (int j = 0; j < 4; ++j)
    cvt_unit(gthr + j * ((T_TOKENS / GTB) * 256), W1, W2, wsw);

  if (tid < E_NUM) lcnt[tid] = 0;
  __syncthreads();

  int t0 = blockIdx.x * GTB;
#pragma unroll 1
  for (int i = 0; i < GTB / 4; ++i){
    int tl = wave * (GTB / 4) + i;
    int t = t0 + tl;
    f32x4 xv = *(const f32x4*)(x + (size_t)t * D_DIM + 4*lane);
    float s[E_NUM];
#pragma unroll
    for (int e = 0; e < E_NUM; ++e){
      f32x4 w = *(const f32x4*)(Wg + e*D_DIM + 4*lane);
      s[e] = xv.x*w.x + xv.y*w.y + xv.z*w.z + xv.w*w.w;
    }
#pragma unroll
    for (int off = 32; off; off >>= 1){
#pragma unroll
      for (int e = 0; e < E_NUM; ++e) s[e] += __shfl_xor(s[e], off);
    }
#pragma unroll
    for (int e = 0; e < E_NUM; ++e) s[e] += bg[e];
    int e0 = 0; float v0 = s[0];
#pragma unroll
    for (int e = 1; e < E_NUM; ++e) if (s[e] > v0){ v0 = s[e]; e0 = e; }
    int e1 = -1; float v1 = -3.4e38f;
#pragma unroll
    for (int e = 0; e < E_NUM; ++e){
      if (e == e0) continue;
      if (s[e] > v1){ v1 = s[e]; e1 = e; }
    }
    float ex = __expf(v1 - v0);
    float inv = 1.f / (1.f + ex);
    float p0 = inv, p1 = ex * inv;
    if (lane == 0){
      int li = tl * 2;
      int pos0 = atomicAdd(&lcnt[e0], 1);
      int pos1 = atomicAdd(&lcnt[e1], 1);
      aexp[li]   = (unsigned char)e0; apos[li]   = (short)pos0;
      aexp[li+1] = (unsigned char)e1; apos[li+1] = (short)pos1;
      f32x4 rr; rr.x = p0; rr.y = p1; rr.z = (float)e0; rr.w = (float)e1;
      *(f32x4*)(rrec + (size_t)t * 4) = rr;
    }
  }
  __syncthreads();
  if (tid < E_NUM) lbase[tid] = atomicAdd(counts + tid*16, lcnt[tid]);
  __syncthreads();
  if (tid < GTB * 2){
    int t = t0 + (tid >> 1);
    int e = aexp[tid];
    int idx = lbase[e] + apos[tid];
    tok_ids[e*T_TOKENS + idx] = t | ((tid & 1) << 16);   // token | which-bit
  }
}

// ---- grouped FFN, T3/T4 pipelined: 64 half-chunks (W1c/W2c alternating,
//      16KB each) staged 3-ahead into a 4x16KB ring; counted vmcnt(12)
//      (never 0 in main loop); 2 short barriers per half-chunk.
//      R5 geometry: 128 tok/block, 4 waves x 32 tok, 2 blocks/CU. ----
__global__ __launch_bounds__(256, 2) void ffn_kernel(
  const float* __restrict__ x, const char* __restrict__ wsw,
  const float* __restrict__ b1,
  const int* __restrict__ counts, const int* __restrict__ tok_ids,
  unsigned short* __restrict__ yslot)
{
  const int e    = blockIdx.x & 7;           // expert -> XCD pinning
  const int tile = blockIdx.x >> 3;
  const int cnt  = counts[e * 16];
  const int base = tile * MT;
  if (base >= cnt) return;

  __shared__ __align__(1024) unsigned short Wr[4][8192];    // 4 x 16KB ring
  __shared__ __align__(16)   float b1s[H_DIM];              // 4KB
  __shared__ int sTok[MT];                                  // 512B

  const int tid = threadIdx.x, wave = tid >> 6, lane = tid & 63;
  const int mrow = lane & 15, qj = lane >> 4;
  const char* wexp = wsw + ((size_t)(e * NCHUNK) << 15);

  // half-chunk j: 16KB at chunk (j>>1), half (j&1); ring slot j&3; 4 loads/wave
  auto stage = [&](int j){
    const char* src = wexp + ((size_t)(j >> 1) << 15) + ((size_t)(j & 1) << 14);
    char* dst = (char*)&Wr[j & 3][0];
#pragma unroll
    for (int i = 0; i < 4; ++i){
      int ub = i * 4096 + wave * 1024;
      __builtin_amdgcn_global_load_lds(
        (glb_u32*)(src + ub + lane * 16),
        (lds_u32*)(dst + ub), 16, 0, 0);
    }
  };

  if (tid < MT){
    int idx = base + tid;
    sTok[tid] = (idx < cnt) ? tok_ids[e*T_TOKENS + idx] : -1;
  }
  *(f32x4*)&b1s[tid * 4] = ((const f32x4*)(b1 + e*H_DIM))[tid];
  __syncthreads();

  // gather x B-fragments into registers (32 tokens/wave, full D)
  s16x8 afr[2][8];
#pragma unroll
  for (int ti = 0; ti < 2; ++ti){
    int ent = sTok[wave*32 + ti*16 + mrow];
    int tk = ent & 0xFFFF;
    const f32x4* src = (const f32x4*)(x + (size_t)(ent < 0 ? 0 : tk) * D_DIM);
#pragma unroll
    for (int k = 0; k < 8; ++k){
      f32x4 a = src[k*8 + qj*2];
      f32x4 b = src[k*8 + qj*2 + 1];
      s16x8 f;
      f[0]=(short)f2bf(a.x); f[1]=(short)f2bf(a.y); f[2]=(short)f2bf(a.z); f[3]=(short)f2bf(a.w);
      f[4]=(short)f2bf(b.x); f[5]=(short)f2bf(b.y); f[6]=(short)f2bf(b.z); f[7]=(short)f2bf(b.w);
      if (ent < 0) f = (s16x8)(short)0;
      afr[ti][k] = f;
    }
  }
  // drain gather so ONLY stage loads occupy the vmcnt queue from here on
  asm volatile("s_waitcnt vmcnt(0)" ::: "memory");

  // prologue staging: 3 half-chunks in flight (12 loads/wave)
  stage(0); stage(1); stage(2);

  const int lb = lane * 16;   // fragment-major per-lane byte offset

  f32x4 yacc[16][2];
#pragma unroll
  for (int m = 0; m < 16; ++m){
    yacc[m][0] = (f32x4){0.f,0.f,0.f,0.f};
    yacc[m][1] = (f32x4){0.f,0.f,0.f,0.f};
  }
  f32x4 hacc[2][2];

  // phase 1 of chunk c: reads ring slot (c&1)*2, builds hacc
  auto phase1 = [&](int c){
    const char* Wb = (const char*)&Wr[(c & 1) * 2][0];
    __builtin_amdgcn_s_setprio(1);
    f32x4 h00 = (f32x4){0.f,0.f,0.f,0.f}, h01 = (f32x4){0.f,0.f,0.f,0.f};
    f32x4 h10 = (f32x4){0.f,0.f,0.f,0.f}, h11 = (f32x4){0.f,0.f,0.f,0.f};
#pragma unroll
    for (int ks = 0; ks < 8; ++ks){
      s16x8 wa = *(const s16x8*)(Wb + lb + (ks*2    )*1024);
      s16x8 wb = *(const s16x8*)(Wb + lb + (ks*2 + 1)*1024);
      h00 = MFMA(wa, afr[0][ks], h00, 0, 0, 0);
      h01 = MFMA(wa, afr[1][ks], h01, 0, 0, 0);
      h10 = MFMA(wb, afr[0][ks], h10, 0, 0, 0);
      h11 = MFMA(wb, afr[1][ks], h11, 0, 0, 0);
    }
    hacc[0][0] = h00; hacc[0][1] = h01;
    hacc[1][0] = h10; hacc[1][1] = h11;
    __builtin_amdgcn_s_setprio(0);
  };

  // phase 2 of chunk c: pack hacc, reads ring slot (c&1)*2+1, updates yacc
  auto phase2 = [&](int c){
    f32x4 bv0 = *(const f32x4*)&b1s[c*32 + qj*4];
    f32x4 bv1 = *(const f32x4*)&b1s[c*32 + 16 + qj*4];
    s16x8 pb0, pb1;
    {
      f32x4 h0 = hacc[0][0], h1 = hacc[1][0];
      h0.x = fmaxf(h0.x + bv0.x, 0.f); h0.y = fmaxf(h0.y + bv0.y, 0.f);
      h0.z = fmaxf(h0.z + bv0.z, 0.f); h0.w = fmaxf(h0.w + bv0.w, 0.f);
      h1.x = fmaxf(h1.x + bv1.x, 0.f); h1.y = fmaxf(h1.y + bv1.y, 0.f);
      h1.z = fmaxf(h1.z + bv1.z, 0.f); h1.w = fmaxf(h1.w + bv1.w, 0.f);
      u32x4 pw;
      pw.x = cvtpk(h0.x, h0.y); pw.y = cvtpk(h0.z, h0.w);
      pw.z = cvtpk(h1.x, h1.y); pw.w = cvtpk(h1.z, h1.w);
      pb0 = __builtin_bit_cast(s16x8, pw);
    }
    {
      f32x4 h0 = hacc[0][1], h1 = hacc[1][1];
      h0.x = fmaxf(h0.x + bv0.x, 0.f); h0.y = fmaxf(h0.y + bv0.y, 0.f);
      h0.z = fmaxf(h0.z + bv0.z, 0.f); h0.w = fmaxf(h0.w + bv0.w, 0.f);
      h1.x = fmaxf(h1.x + bv1.x, 0.f); h1.y = fmaxf(h1.y + bv1.y, 0.f);
      h1.z = fmaxf(h1.z + bv1.z, 0.f); h1.w = fmaxf(h1.w + bv1.w, 0.f);
      u32x4 pw;
      pw.x = cvtpk(h0.x, h0.y); pw.y = cvtpk(h0.z, h0.w);
      pw.z = cvtpk(h1.x, h1.y); pw.w = cvtpk(h1.z, h1.w);
      pb1 = __builtin_bit_cast(s16x8, pw);
    }
    const char* Wl = (const char*)&Wr[(c & 1) * 2 + 1][0];
    __builtin_amdgcn_s_setprio(1);
#pragma unroll
    for (int m = 0; m < 16; ++m){
      s16x8 lf = *(const s16x8*)(Wl + lb + m*1024);
      yacc[m][0] = MFMA(lf, pb0, yacc[m][0], 0, 0, 0);
      yacc[m][1] = MFMA(lf, pb1, yacc[m][1], 0, 0, 0);
    }
    __builtin_amdgcn_s_setprio(0);
  };

#define VM_BAR(N) asm volatile("s_waitcnt vmcnt(" #N ")\ns_barrier" ::: "memory")
#define RD_BAR()  asm volatile("s_waitcnt lgkmcnt(0)\ns_barrier" ::: "memory")

  // main loop: chunks 0..29 — stages always valid, vmcnt stays at 12
#pragma unroll 1
  for (int c = 0; c < 30; ++c){
    stage(2*c + 3);
    VM_BAR(12);          // stage(2c) landed for ALL waves; 3 stages in flight
    phase1(c);
    RD_BAR();            // slot (2c)&3 reads retired -> safe to overwrite
    stage(2*c + 4);
    VM_BAR(12);          // stage(2c+1) landed
    phase2(c);
    RD_BAR();
  }
  // c = 30 (hc 60,61): stage(63) is the last issue
  stage(63);
  VM_BAR(12);  phase1(30);  RD_BAR();
  VM_BAR(8);   phase2(30);  RD_BAR();
  // c = 31 (hc 62,63): drain tail
  VM_BAR(4);   phase1(31);  RD_BAR();
  VM_BAR(0);   phase2(31);

#undef VM_BAR
#undef RD_BAR

  // ---- store: yslot[2*tok+which][d] = bf16(y), packed b32, no atomics ----
#pragma unroll
  for (int ti = 0; ti < 2; ++ti){
    int ent = sTok[wave*32 + ti*16 + mrow];
    if (ent < 0) continue;
    int slot = ((ent & 0xFFFF) << 1) | ((ent >> 16) & 1);
    unsigned short* dst = yslot + (size_t)slot * 256;
#pragma unroll
    for (int m = 0; m < 16; ++m){
      unsigned lo = cvtpk(yacc[m][ti][0], yacc[m][ti][1]);
      unsigned hi = cvtpk(yacc[m][ti][2], yacc[m][ti][3]);
      *(unsigned*)(dst + m*16 + qj*4)     = lo;   // d = m*16 + qj*4 + {0,1}
      *(unsigned*)(dst + m*16 + qj*4 + 2) = hi;   // d = ... + {2,3}
    }
  }
}

// ---- combine: out[t] = p0*(y0+b2[e0]) + p1*(y1+b2[e1]); in-place over slots ----
__global__ __launch_bounds__(256) void combine_kernel(
    const float* __restrict__ rrec, const float* __restrict__ b2,
    float* __restrict__ out)
{
  int t = blockIdx.x * 4 + (threadIdx.x >> 6);
  int lane = threadIdx.x & 63;
  f32x4 rr = *(const f32x4*)(rrec + (size_t)t * 4);
  float p0 = rr.x, p1 = rr.y;
  int e0 = (int)rr.z, e1 = (int)rr.w;
  const u16x4* s0 = (const u16x4*)((const unsigned short*)out + (size_t)t * 512);
  u16x4 a = s0[lane];        // slot 2t   : cols lane*4..+3
  u16x4 b = s0[64 + lane];   // slot 2t+1
  f32x4 z0 = *(const f32x4*)(b2 + e0*D_DIM + 4*lane);
  f32x4 z1 = *(const f32x4*)(b2 + e1*D_DIM + 4*lane);
  f32x4 o;
  o.x = p0*(bf2f(a.x) + z0.x) + p1*(bf2f(b.x) + z1.x);
  o.y = p0*(bf2f(a.y) + z0.y) + p1*(bf2f(b.y) + z1.y);
  o.z = p0*(bf2f(a.z) + z0.z) + p1*(bf2f(b.z) + z1.z);
  o.w = p0*(bf2f(a.w) + z0.w) + p1*(bf2f(b.w) + z1.w);
  *(f32x4*)(out + (size_t)t * D_DIM + 4*lane) = o;
}

extern "C" void kernel_launch(void* const* d_in, const int* in_sizes, int n_in,
                              void* d_out, int out_size, void* d_ws, size_t ws_size,
                              hipStream_t stream) {
  const float* x  = (const float*)d_in[0];
  const float* Wg = (const float*)d_in[1];
  const float* bg = (const float*)d_in[2];
  const float* W1 = (const float*)d_in[3];
  const float* b1 = (const float*)d_in[4];
  const float* W2 = (const float*)d_in[5];
  const float* b2 = (const float*)d_in[6];
  float* out = (float*)d_out;
  char* ws = (char*)d_ws;

  char*  wsw     = ws;                        // 8,388,608 B fragment-major weights
  int*   counts  = (int*)  (ws + 8388608);    // 512 B (8 x 64B lines)
  int*   tok_ids = (int*)  (ws + 8389632);    // 2,097,152 B
  float* rrec    = (float*)(ws + 10486784);   // 1,048,576 B (f32x4 per token)

  hipMemsetAsync(counts, 0, 512, stream);
  gate_kernel<<<T_TOKENS/GTB, 256, 0, stream>>>(x, Wg, bg, W1, W2, wsw,
                                                counts, tok_ids, rrec);
  ffn_kernel<<<E_NUM * NTILE, 256, 0, stream>>>(x, wsw, b1, counts, tok_ids,
                                                (unsigned short*)d_out);
  combine_kernel<<<T_TOKENS/4, 256, 0, stream>>>(rrec, b2, out);
}